// Round 8
// baseline (1213.987 us; speedup 1.0000x reference)
//
#include <hip/hip_runtime.h>
#include <cmath>

// GCN 2-layer, dims 1 -> 16 -> 2, N=100K, E=6.4M.
//
// Model (R1..R20, counter-validated):
//  - 4 edge passes: aggf=45.5us (top-5), deg/agg2f/scatter each <43.
//    Node kernels ~11us. Sum ~165 -> ~60us is inter-dispatch overhead.
//  - Passes resist tuning: VALU 6%, HBM 8%, LDS-conf 0, occ 59%; pair-cell
//    ILP regressed (+7us, R18); occupancy lever exhausted (R20 null).
//  - Dead ends (counter-proven): atomic-free gathers (R14/15), global
//    atomics (R16: 29G/s), cooperative fusion (R17/R19: ~550us, device-wide
//    sync = cold L2 + fixed residency).
// R21: delete 3 launches WITHOUT grid.sync. prep/mlp/out have per-BUCKET
// deps only -> fuse as last-block-of-bucket finishers into deg/aggf/agg2f:
// dump partial -> threadfence -> atomicAdd(done[k]); the block seeing
// old==C-1 acquires (fence) and computes bucket k's 2048 nodes inline.
// done[] zeroed by scatter block 0 (kernel-boundary visibility). 7->4
// dispatches; node work overlaps edge work.

static constexpr int CSH   = 11;           // log2 bucket width
static constexpr int CW    = 1 << CSH;     // 2048 nodes / bucket
static constexpr int MAXNC = 64;           // n <= 131072
static constexpr int NB1   = 512;          // scatter blocks / segments

__host__ __device__ __forceinline__ int chunk_of(int e) {
    return ((e + NB1 * 4 - 1) / (NB1 * 4)) * 4;   // 4-aligned per-block chunk
}

// ---- 1) scatter into padded block-local regions + zero done[] ----
__global__ __launch_bounds__(1024) void k_scatter(const int* __restrict__ row,
        const int* __restrict__ col, int* __restrict__ P1, int* __restrict__ CNT,
        int* __restrict__ done, int e, int NC, int PAD) {
    __shared__ int cur[MAXNC];
    const int b = blockIdx.x, tid = threadIdx.x;
    if (b == 0) for (int q = tid; q < 3 * MAXNC; q += 1024) done[q] = 0;
    for (int j = tid; j < NC; j += 1024) cur[j] = 0;
    __syncthreads();
    const int chunk = chunk_of(e);
    const int lo = b * chunk, end = min(lo + chunk, e);
    const size_t rbase = (size_t)b * NC * PAD;
    for (int i0 = lo + tid * 8; i0 + 7 < end; i0 += 8192) {
        int4 c4a = *reinterpret_cast<const int4*>(col + i0);
        int4 c4b = *reinterpret_cast<const int4*>(col + i0 + 4);
        int4 r4a = *reinterpret_cast<const int4*>(row + i0);
        int4 r4b = *reinterpret_cast<const int4*>(row + i0 + 4);
        int ca[8] = {c4a.x, c4a.y, c4a.z, c4a.w, c4b.x, c4b.y, c4b.z, c4b.w};
        int ra[8] = {r4a.x, r4a.y, r4a.z, r4a.w, r4b.x, r4b.y, r4b.z, r4b.w};
#pragma unroll
        for (int m = 0; m < 8; ++m) {
            int k = ca[m] >> CSH;
            int pos = atomicAdd(&cur[k], 1);
            if (pos < PAD)   // overflow guard (P ~1e-12 at PAD = mean+8sigma)
                P1[rbase + (size_t)k * PAD + pos] = (ra[m] << CSH) | (ca[m] & (CW - 1));
        }
    }
    const int tailStart = lo + ((end - lo) & ~7);
    for (int i = tailStart + tid; i < end; i += 1024) {
        int c = col[i], r = row[i];
        int k = c >> CSH;
        int pos = atomicAdd(&cur[k], 1);
        if (pos < PAD)
            P1[rbase + (size_t)k * PAD + pos] = (r << CSH) | (c & (CW - 1));
    }
    __syncthreads();
    for (int j = tid; j < NC; j += 1024) CNT[b * NC + j] = min(cur[j], PAD);
}

// ---- 2) deg pass + fused per-bucket prep finisher ----
__global__ __launch_bounds__(512) void k_degp(const int* __restrict__ P1,
        const int* __restrict__ CNT, int* __restrict__ Pd,
        const float* __restrict__ x, float* __restrict__ dis,
        float* __restrict__ t, float* __restrict__ degf,
        int* __restrict__ done, int n, int NC, int C, int PAD) {
    __shared__ __align__(16) int bin[CW];
    __shared__ int isLast;
    const int k = blockIdx.x / C, j = blockIdx.x % C;
    const int tid = threadIdx.x, wave = tid >> 6, lane = tid & 63;
    for (int q = tid; q < CW; q += 512) bin[q] = 0;
    __syncthreads();
    const int b0 = (j * NB1) / C, b1 = ((j + 1) * NB1) / C;
    for (int b = b0 + wave; b < b1; b += 8) {
        const int cnt = CNT[b * NC + k];
        const int* seg = P1 + ((size_t)b * NC + k) * PAD;
        const int nv = cnt & ~3;
        for (int i = lane * 4; i < nv; i += 256) {
            int4 a = *reinterpret_cast<const int4*>(seg + i);
            atomicAdd(&bin[a.x & (CW - 1)], 1); atomicAdd(&bin[a.y & (CW - 1)], 1);
            atomicAdd(&bin[a.z & (CW - 1)], 1); atomicAdd(&bin[a.w & (CW - 1)], 1);
        }
        for (int i = nv + lane; i < cnt; i += 64)
            atomicAdd(&bin[seg[i] & (CW - 1)], 1);
    }
    __syncthreads();
    int4* o4 = reinterpret_cast<int4*>(Pd + ((size_t)k * C + j) * CW);
    const int4* b4 = reinterpret_cast<const int4*>(bin);
    for (int q = tid; q < CW / 4; q += 512) o4[q] = b4[q];
    // ---- finisher: last block of bucket k does prep for its 2048 nodes ----
    __threadfence();                       // release own dump
    __syncthreads();                       // all threads' dumps fenced
    if (tid == 0) isLast = (atomicAdd(&done[k], 1) == C - 1);
    __syncthreads();
    if (!isLast) return;
    __threadfence();                       // acquire other blocks' dumps
    const int cbase = k << CSH;
    for (int l = tid; l < CW; l += 512) {
        int c = cbase + l;
        if (c >= n) break;
        int d = 0;
        for (int jj = 0; jj < C; ++jj) d += Pd[((size_t)k * C + jj) * CW + l];
        degf[c] = (float)d;
        float di = rsqrtf(1.0f + (float)d);
        dis[c] = di;
        t[c] = di * x[c];
    }
}

// ---- 3) layer-1 aggregate + fused per-bucket MLP finisher ----
__global__ __launch_bounds__(512) void k_aggfm(const int* __restrict__ P1,
        const int* __restrict__ CNT, const float* __restrict__ t,
        float* __restrict__ Pf, const float* __restrict__ dis,
        const float* __restrict__ W1, const float* __restrict__ b1,
        const float* __restrict__ W2, float2* __restrict__ u,
        int* __restrict__ done, int n, int NC, int C, int PAD) {
    __shared__ __align__(16) float bin[CW];
    __shared__ int isLast;
    const int k = blockIdx.x / C, j = blockIdx.x % C;
    const int tid = threadIdx.x, wave = tid >> 6, lane = tid & 63;
    for (int q = tid; q < CW; q += 512) bin[q] = 0.0f;
    __syncthreads();
    const int b0 = (j * NB1) / C, b1e = ((j + 1) * NB1) / C;
    for (int b = b0 + wave; b < b1e; b += 8) {
        const int cnt = CNT[b * NC + k];
        const int* seg = P1 + ((size_t)b * NC + k) * PAD;
        const int nv = cnt & ~3;
        for (int i = lane * 4; i < nv; i += 256) {
            int4 a = *reinterpret_cast<const int4*>(seg + i);
            float v0 = t[a.x >> CSH], v1 = t[a.y >> CSH];
            float v2 = t[a.z >> CSH], v3 = t[a.w >> CSH];
            atomicAdd(&bin[a.x & (CW - 1)], v0); atomicAdd(&bin[a.y & (CW - 1)], v1);
            atomicAdd(&bin[a.z & (CW - 1)], v2); atomicAdd(&bin[a.w & (CW - 1)], v3);
        }
        for (int i = nv + lane; i < cnt; i += 64) {
            int p = seg[i];
            atomicAdd(&bin[p & (CW - 1)], t[p >> CSH]);
        }
    }
    __syncthreads();
    float4* o4 = reinterpret_cast<float4*>(Pf + ((size_t)k * C + j) * CW);
    const float4* b4 = reinterpret_cast<const float4*>(bin);
    for (int q = tid; q < CW / 4; q += 512) o4[q] = b4[q];
    // ---- finisher: last block of bucket k runs the MLP for its nodes ----
    __threadfence();
    __syncthreads();
    if (tid == 0) isLast = (atomicAdd(&done[k], 1) == C - 1);
    __syncthreads();
    if (!isLast) return;
    __threadfence();
    const int cbase = k << CSH;
    for (int l = tid; l < CW; l += 512) {
        int c = cbase + l;
        if (c >= n) break;
        float S = 0.0f;
        for (int jj = 0; jj < C; ++jj) S += Pf[((size_t)k * C + jj) * CW + l];
        float di = dis[c];
        float s = di * (S + t[c]);
        float a0 = 0.0f, a1 = 0.0f;
#pragma unroll
        for (int m = 0; m < 16; ++m) {
            float hh = fmaxf(fmaf(s, W1[m], b1[m]), 0.0f);
            a0 = fmaf(W2[m],      hh, a0);
            a1 = fmaf(W2[16 + m], hh, a1);
        }
        u[c] = make_float2(di * a0, di * a1);
    }
}

// ---- 4) layer-2 aggregate (u64 fixed-point) + fused output finisher ----
__device__ __forceinline__ unsigned long long pack_u(float2 uv) {
    float cx = fminf(fmaxf(uv.x, -15.9f), 15.9f);
    float cy = fminf(fmaxf(uv.y, -15.9f), 15.9f);
    unsigned int tx = (unsigned int)__float2int_rn(fmaf(cx, 524288.0f, 8388608.0f));
    unsigned int ty = (unsigned int)__float2int_rn(fmaf(cy, 524288.0f, 8388608.0f));
    return ((unsigned long long)ty << 32) | tx;
}

__global__ __launch_bounds__(512) void k_agg2o(const int* __restrict__ P1,
        const int* __restrict__ CNT, const float2* __restrict__ u,
        unsigned long long* __restrict__ Pq, const float* __restrict__ dis,
        const float* __restrict__ degf, const float* __restrict__ b2,
        float2* __restrict__ out, int* __restrict__ done,
        int n, int NC, int C, int PAD) {
    __shared__ unsigned long long bin[CW];   // 16 KB
    __shared__ int isLast;
    const int k = blockIdx.x / C, j = blockIdx.x % C;
    const int tid = threadIdx.x, wave = tid >> 6, lane = tid & 63;
    for (int q = tid; q < CW; q += 512) bin[q] = 0ull;
    __syncthreads();
    const int b0 = (j * NB1) / C, b1e = ((j + 1) * NB1) / C;
    for (int b = b0 + wave; b < b1e; b += 8) {
        const int cnt = CNT[b * NC + k];
        const int* seg = P1 + ((size_t)b * NC + k) * PAD;
        const int nv = cnt & ~3;
        for (int i = lane * 4; i < nv; i += 256) {
            int4 a = *reinterpret_cast<const int4*>(seg + i);
            unsigned long long q0 = pack_u(u[a.x >> CSH]);
            unsigned long long q1 = pack_u(u[a.y >> CSH]);
            unsigned long long q2 = pack_u(u[a.z >> CSH]);
            unsigned long long q3 = pack_u(u[a.w >> CSH]);
            atomicAdd(&bin[a.x & (CW - 1)], q0); atomicAdd(&bin[a.y & (CW - 1)], q1);
            atomicAdd(&bin[a.z & (CW - 1)], q2); atomicAdd(&bin[a.w & (CW - 1)], q3);
        }
        for (int i = nv + lane; i < cnt; i += 64) {
            int p = seg[i];
            atomicAdd(&bin[p & (CW - 1)], pack_u(u[p >> CSH]));
        }
    }
    __syncthreads();
    unsigned long long* o = Pq + ((size_t)k * C + j) * CW;
    for (int q = tid; q < CW; q += 512) o[q] = bin[q];
    // ---- finisher: last block of bucket k unpacks + writes the output ----
    __threadfence();
    __syncthreads();
    if (tid == 0) isLast = (atomicAdd(&done[k], 1) == C - 1);
    __syncthreads();
    if (!isLast) return;
    __threadfence();
    const int cbase = k << CSH;
    for (int l = tid; l < CW; l += 512) {
        int c = cbase + l;
        if (c >= n) break;
        unsigned long long S = 0ull;
        for (int jj = 0; jj < C; ++jj) S += Pq[((size_t)k * C + jj) * CW + l];
        double dg = (double)degf[c] * 8388608.0;
        double sx = ((double)(unsigned int)(S & 0xffffffffULL) - dg) * (1.0 / 524288.0);
        double sy = ((double)(unsigned int)(S >> 32)            - dg) * (1.0 / 524288.0);
        float di = dis[c];
        float2 uc = u[c];
        out[c] = make_float2(b2[0] + di * ((float)sx + uc.x),
                             b2[1] + di * ((float)sy + uc.y));
    }
}

// ---------- generic atomic fallback (any n/e, slow but correct) ----------
__global__ void f_init_deg(float* deg, int n) {
    int i = blockIdx.x * blockDim.x + threadIdx.x;
    if (i < n) deg[i] = 1.0f;
}
__global__ void f_deg(const int* col, float* deg, int e) {
    int i = blockIdx.x * blockDim.x + threadIdx.x;
    if (i < e) atomicAdd(&deg[col[i]], 1.0f);
}
__global__ void f_dis_self(const float* x, float* deg_dis, float* s, int n) {
    int i = blockIdx.x * blockDim.x + threadIdx.x;
    if (i < n) { float di = rsqrtf(deg_dis[i]); deg_dis[i] = di; s[i] = di * di * x[i]; }
}
__global__ void f_agg1(const int* row, const int* col, const float* dis,
                       const float* x, float* s, int e) {
    int i = blockIdx.x * blockDim.x + threadIdx.x;
    if (i < e) { int r = row[i], c = col[i]; atomicAdd(&s[c], dis[r] * dis[c] * x[r]); }
}
__global__ void f_mlp(const float* s, const float* dis, const float* W1,
                      const float* b1, const float* W2, const float* b2,
                      float* h2, float* out, int n) {
    int i = blockIdx.x * blockDim.x + threadIdx.x;
    if (i < n) {
        float sv = s[i], a0 = 0.0f, a1 = 0.0f;
#pragma unroll
        for (int j = 0; j < 16; ++j) {
            float h1 = fmaxf(sv * W1[j] + b1[j], 0.0f);
            a0 = fmaf(W2[j], h1, a0); a1 = fmaf(W2[16 + j], h1, a1);
        }
        h2[2 * i] = a0; h2[2 * i + 1] = a1;
        float d2 = dis[i] * dis[i];
        out[2 * i] = b2[0] + d2 * a0; out[2 * i + 1] = b2[1] + d2 * a1;
    }
}
__global__ void f_agg2(const int* row, const int* col, const float* dis,
                       const float* h2, float* out, int e) {
    int i = blockIdx.x * blockDim.x + threadIdx.x;
    if (i < e) {
        int r = row[i], c = col[i];
        float nm = dis[r] * dis[c];
        float2 hv = *reinterpret_cast<const float2*>(&h2[2 * r]);
        atomicAdd(&out[2 * c], nm * hv.x);
        atomicAdd(&out[2 * c + 1], nm * hv.y);
    }
}
// -------------------------------------------------------------------------

extern "C" void kernel_launch(void* const* d_in, const int* in_sizes, int n_in,
                              void* d_out, int out_size, void* d_ws, size_t ws_size,
                              hipStream_t stream) {
    const float* x  = (const float*)d_in[0];
    const int*   ei = (const int*)d_in[1];
    const float* W1 = (const float*)d_in[2];
    const float* b1 = (const float*)d_in[3];
    const float* W2 = (const float*)d_in[4];
    const float* b2 = (const float*)d_in[5];

    const int n = in_sizes[0];
    const int e = in_sizes[1] / 2;
    const int* row = ei;
    const int* col = ei + e;

    const int NC = (n + CW - 1) >> CSH;
    const size_t NCW = (size_t)NC * CW;

    // PAD = mean + 8*sigma + 32 (binomial tail; overflow P ~1e-12/cell)
    const int chunk = chunk_of(e);
    const int lam = NC > 0 ? chunk / NC : 0;
    int PAD = lam + 8 * (int)std::sqrt((double)(lam > 0 ? lam : 1)) + 32;
    PAD = (PAD + 3) & ~3;

    // ws (4B): P1 | CNT | dis[n] | t[n] | degf[n] | u[2n] | done[3*MAXNC] | Pp
    const size_t ws4 = ws_size / 4;
    const size_t p1sz = (size_t)NB1 * NC * PAD;
    size_t base4 = p1sz + (size_t)NB1 * NC + 5ull * (size_t)n + 3 * MAXNC;
    base4 = (base4 + 3) & ~(size_t)3;
    long long avail = (long long)ws4 - (long long)base4;
    int Cs = (avail > 0) ? (int)min((long long)32, avail / (long long)NCW) : 0;
    int Cv = (avail > 0) ? (int)min((long long)24, avail / (long long)(2 * NCW)) : 0;

    // Guards: u64 packing needs indeg<256 (e<=100n); NC>=4 avoids cursor
    // same-address meltdown; ws must fit padded regions + partials.
    const int gn = (n + 255) / 256;
    if (NC > MAXNC || NC < 4 || Cs < 2 || Cv < 2 ||
        (long long)e > 100ll * (long long)n) {
        float* dis = (float*)d_ws; float* s = dis + n; float* h2 = s + n;
        const int ge = (e + 255) / 256;
        f_init_deg<<<gn, 256, 0, stream>>>(dis, n);
        f_deg<<<ge, 256, 0, stream>>>(col, dis, e);
        f_dis_self<<<gn, 256, 0, stream>>>(x, dis, s, n);
        f_agg1<<<ge, 256, 0, stream>>>(row, col, dis, x, s, e);
        f_mlp<<<gn, 256, 0, stream>>>(s, dis, W1, b1, W2, b2, h2, (float*)d_out, n);
        f_agg2<<<ge, 256, 0, stream>>>(row, col, dis, h2, (float*)d_out, e);
        return;
    }

    int*    P1   = (int*)d_ws;
    int*    CNT  = P1 + p1sz;
    float*  dis  = (float*)(CNT + (size_t)NB1 * NC);
    float*  t    = dis + n;
    float*  degf = t + n;
    float2* u    = (float2*)(degf + n);
    int*    done = (int*)(degf + n) + 2 * (size_t)n;     // after u[2n]
    float*  Pp   = (float*)((char*)d_ws + base4 * 4);    // partials

    k_scatter<<<NB1, 1024, 0, stream>>>(row, col, P1, CNT, done, e, NC, PAD);
    k_degp   <<<NC * Cs, 512, 0, stream>>>(P1, CNT, (int*)Pp, x, dis, t, degf,
                                           done, n, NC, Cs, PAD);
    k_aggfm  <<<NC * Cs, 512, 0, stream>>>(P1, CNT, t, Pp, dis, W1, b1, W2, u,
                                           done + MAXNC, n, NC, Cs, PAD);
    k_agg2o  <<<NC * Cv, 512, 0, stream>>>(P1, CNT, u, (unsigned long long*)Pp,
                                           dis, degf, b2, (float2*)d_out,
                                           done + 2 * MAXNC, n, NC, Cv, PAD);
}

// Round 9
// 226.105 us; speedup vs baseline: 5.3691x; 5.3691x over previous
//
#include <hip/hip_runtime.h>
#include <cmath>

// GCN 2-layer, dims 1 -> 16 -> 2, N=100K, E=6.4M.
//
// FINAL MODEL (R1..R21, counter-validated):
//  - Each of the 4 edge passes (scatter, deg, aggf, agg2u64) sits at the
//    DS-pipe lane-serialized atomic floor: 6.4M lane-atomics x ~4.2cyc /
//    256CU / 2.4GHz = 43.5us. Signature: VALU 6%, HBM 8%, bank-conf 0,
//    occ 59% -> no classic roofline axis is loaded; the DS atomic unit is.
//  - Dependency chain deg -> dis,t -> agg1 -> mlp -> agg2 forces 4 edge
//    passes (dis[r] inside the aggregation sum cannot be factored out).
//  - Ledger: 4x43.5 + ~11us node kernels + ~30-40us launch/tail = ~227us.
//  - Counter-proven DEAD ENDS (do not retry):
//    * atomic-free slot gathers: write-amp 185MB + dependent-load latency
//      (~65us/pass) [R14/R15]
//    * global atomicAdd: 29G atomics/s write-through on 8 XCDs [R16]
//    * cooperative grid.sync fusion: ~550us, device-wide sync [R17/R19]
//    * per-thread pair-cell ILP: +7us/pass VALU mask overhead [R18]
//    * more waves: occupancy lever exhausted [R20 null]
//    * threadfence+atomic per-bucket finisher fusion: 1214us — device-scope
//      release = L2 writeback/invalidate drain per block [R21]
// R22 = exact revert to R20 (226.9us best). This is the structural floor
// of this algorithm on gfx950.

static constexpr int CSH   = 11;           // log2 bucket width
static constexpr int CW    = 1 << CSH;     // 2048 nodes / bucket
static constexpr int MAXNC = 64;           // n <= 131072
static constexpr int NB1   = 512;          // scatter blocks / segments

__host__ __device__ __forceinline__ int chunk_of(int e) {
    return ((e + NB1 * 4 - 1) / (NB1 * 4)) * 4;   // 4-aligned per-block chunk
}

// ---- 1) scatter into padded block-local regions, local cursors ----
__global__ __launch_bounds__(1024) void k_scatter(const int* __restrict__ row,
        const int* __restrict__ col, int* __restrict__ P1, int* __restrict__ CNT,
        int e, int NC, int PAD) {
    __shared__ int cur[MAXNC];
    const int b = blockIdx.x, tid = threadIdx.x;
    for (int j = tid; j < NC; j += 1024) cur[j] = 0;
    __syncthreads();
    const int chunk = chunk_of(e);
    const int lo = b * chunk, end = min(lo + chunk, e);
    const size_t rbase = (size_t)b * NC * PAD;
    for (int i0 = lo + tid * 8; i0 + 7 < end; i0 += 8192) {
        int4 c4a = *reinterpret_cast<const int4*>(col + i0);
        int4 c4b = *reinterpret_cast<const int4*>(col + i0 + 4);
        int4 r4a = *reinterpret_cast<const int4*>(row + i0);
        int4 r4b = *reinterpret_cast<const int4*>(row + i0 + 4);
        int ca[8] = {c4a.x, c4a.y, c4a.z, c4a.w, c4b.x, c4b.y, c4b.z, c4b.w};
        int ra[8] = {r4a.x, r4a.y, r4a.z, r4a.w, r4b.x, r4b.y, r4b.z, r4b.w};
#pragma unroll
        for (int m = 0; m < 8; ++m) {
            int k = ca[m] >> CSH;
            int pos = atomicAdd(&cur[k], 1);
            if (pos < PAD)   // overflow guard (P ~1e-12 at PAD = mean+8sigma)
                P1[rbase + (size_t)k * PAD + pos] = (ra[m] << CSH) | (ca[m] & (CW - 1));
        }
    }
    const int tailStart = lo + ((end - lo) & ~7);
    for (int i = tailStart + tid; i < end; i += 1024) {
        int c = col[i], r = row[i];
        int k = c >> CSH;
        int pos = atomicAdd(&cur[k], 1);
        if (pos < PAD)
            P1[rbase + (size_t)k * PAD + pos] = (r << CSH) | (c & (CW - 1));
    }
    __syncthreads();
    for (int j = tid; j < NC; j += 1024) CNT[b * NC + j] = min(cur[j], PAD);
}

// ---- 2) degree pass: per-segment int4 loop, LDS int bins ----
__global__ __launch_bounds__(512) void k_deg(const int* __restrict__ P1,
        const int* __restrict__ CNT, int* __restrict__ Pd, int NC, int C, int PAD) {
    __shared__ __align__(16) int bin[CW];
    const int k = blockIdx.x / C, j = blockIdx.x % C;
    const int tid = threadIdx.x, wave = tid >> 6, lane = tid & 63;
    for (int q = tid; q < CW; q += 512) bin[q] = 0;
    __syncthreads();
    const int b0 = (j * NB1) / C, b1 = ((j + 1) * NB1) / C;
    for (int b = b0 + wave; b < b1; b += 8) {
        const int cnt = CNT[b * NC + k];
        const int* seg = P1 + ((size_t)b * NC + k) * PAD;
        const int nv = cnt & ~3;
        for (int i = lane * 4; i < nv; i += 256) {
            int4 a = *reinterpret_cast<const int4*>(seg + i);
            atomicAdd(&bin[a.x & (CW - 1)], 1); atomicAdd(&bin[a.y & (CW - 1)], 1);
            atomicAdd(&bin[a.z & (CW - 1)], 1); atomicAdd(&bin[a.w & (CW - 1)], 1);
        }
        for (int i = nv + lane; i < cnt; i += 64)
            atomicAdd(&bin[seg[i] & (CW - 1)], 1);
    }
    __syncthreads();
    int4* o4 = reinterpret_cast<int4*>(Pd + ((size_t)k * C + j) * CW);
    const int4* b4 = reinterpret_cast<const int4*>(bin);
    for (int q = tid; q < CW / 4; q += 512) o4[q] = b4[q];
}

// ---- 3) layer-1 aggregate: bin[col] += src[row] ----
__global__ __launch_bounds__(512) void k_aggf(const int* __restrict__ P1,
        const int* __restrict__ CNT, const float* __restrict__ src,
        float* __restrict__ Pf, int NC, int C, int PAD) {
    __shared__ __align__(16) float bin[CW];
    const int k = blockIdx.x / C, j = blockIdx.x % C;
    const int tid = threadIdx.x, wave = tid >> 6, lane = tid & 63;
    for (int q = tid; q < CW; q += 512) bin[q] = 0.0f;
    __syncthreads();
    const int b0 = (j * NB1) / C, b1 = ((j + 1) * NB1) / C;
    for (int b = b0 + wave; b < b1; b += 8) {
        const int cnt = CNT[b * NC + k];
        const int* seg = P1 + ((size_t)b * NC + k) * PAD;
        const int nv = cnt & ~3;
        for (int i = lane * 4; i < nv; i += 256) {
            int4 a = *reinterpret_cast<const int4*>(seg + i);
            float v0 = src[a.x >> CSH], v1 = src[a.y >> CSH];
            float v2 = src[a.z >> CSH], v3 = src[a.w >> CSH];
            atomicAdd(&bin[a.x & (CW - 1)], v0); atomicAdd(&bin[a.y & (CW - 1)], v1);
            atomicAdd(&bin[a.z & (CW - 1)], v2); atomicAdd(&bin[a.w & (CW - 1)], v3);
        }
        for (int i = nv + lane; i < cnt; i += 64) {
            int p = seg[i];
            atomicAdd(&bin[p & (CW - 1)], src[p >> CSH]);
        }
    }
    __syncthreads();
    float4* o4 = reinterpret_cast<float4*>(Pf + ((size_t)k * C + j) * CW);
    const float4* b4 = reinterpret_cast<const float4*>(bin);
    for (int q = tid; q < CW / 4; q += 512) o4[q] = b4[q];
}

// ---- 4) layer-2 aggregate: ONE u64 atomic, biased fixed-point ----
__device__ __forceinline__ unsigned long long pack_u(float2 uv) {
    float cx = fminf(fmaxf(uv.x, -15.9f), 15.9f);
    float cy = fminf(fmaxf(uv.y, -15.9f), 15.9f);
    unsigned int tx = (unsigned int)__float2int_rn(fmaf(cx, 524288.0f, 8388608.0f));
    unsigned int ty = (unsigned int)__float2int_rn(fmaf(cy, 524288.0f, 8388608.0f));
    return ((unsigned long long)ty << 32) | tx;
}

__global__ __launch_bounds__(512) void k_agg2f(const int* __restrict__ P1,
        const int* __restrict__ CNT, const float2* __restrict__ u,
        unsigned long long* __restrict__ Pq, int NC, int C, int PAD) {
    __shared__ unsigned long long bin[CW];   // 16 KB
    const int k = blockIdx.x / C, j = blockIdx.x % C;
    const int tid = threadIdx.x, wave = tid >> 6, lane = tid & 63;
    for (int q = tid; q < CW; q += 512) bin[q] = 0ull;
    __syncthreads();
    const int b0 = (j * NB1) / C, b1 = ((j + 1) * NB1) / C;
    for (int b = b0 + wave; b < b1; b += 8) {
        const int cnt = CNT[b * NC + k];
        const int* seg = P1 + ((size_t)b * NC + k) * PAD;
        const int nv = cnt & ~3;
        for (int i = lane * 4; i < nv; i += 256) {
            int4 a = *reinterpret_cast<const int4*>(seg + i);
            unsigned long long q0 = pack_u(u[a.x >> CSH]);
            unsigned long long q1 = pack_u(u[a.y >> CSH]);
            unsigned long long q2 = pack_u(u[a.z >> CSH]);
            unsigned long long q3 = pack_u(u[a.w >> CSH]);
            atomicAdd(&bin[a.x & (CW - 1)], q0); atomicAdd(&bin[a.y & (CW - 1)], q1);
            atomicAdd(&bin[a.z & (CW - 1)], q2); atomicAdd(&bin[a.w & (CW - 1)], q3);
        }
        for (int i = nv + lane; i < cnt; i += 64) {
            int p = seg[i];
            atomicAdd(&bin[p & (CW - 1)], pack_u(u[p >> CSH]));
        }
    }
    __syncthreads();
    unsigned long long* o = Pq + ((size_t)k * C + j) * CW;
    for (int q = tid; q < CW; q += 512) o[q] = bin[q];
}

// ---- 5) node kernels ----
__global__ void k_prep(const int* __restrict__ Pd, const float* __restrict__ x,
        float* __restrict__ dis, float* __restrict__ t, float* __restrict__ degf,
        int n, int C) {
    int c = blockIdx.x * blockDim.x + threadIdx.x;
    if (c >= n) return;
    int k = c >> CSH, l = c & (CW - 1);
    int d = 0;
    for (int j = 0; j < C; ++j) d += Pd[((size_t)k * C + j) * CW + l];
    degf[c] = (float)d;
    float di = rsqrtf(1.0f + (float)d);
    dis[c] = di;
    t[c] = di * x[c];
}

__global__ void k_mlp(const float* __restrict__ Pf, const float* __restrict__ dis,
        const float* __restrict__ t, const float* __restrict__ W1,
        const float* __restrict__ b1, const float* __restrict__ W2,
        float2* __restrict__ u, int n, int C) {
    int c = blockIdx.x * blockDim.x + threadIdx.x;
    if (c >= n) return;
    int k = c >> CSH, l = c & (CW - 1);
    float S = 0.0f;
    for (int j = 0; j < C; ++j) S += Pf[((size_t)k * C + j) * CW + l];
    float di = dis[c];
    float s = di * (S + t[c]);
    float a0 = 0.0f, a1 = 0.0f;
#pragma unroll
    for (int j = 0; j < 16; ++j) {
        float hh = fmaxf(fmaf(s, W1[j], b1[j]), 0.0f);
        a0 = fmaf(W2[j],      hh, a0);
        a1 = fmaf(W2[16 + j], hh, a1);
    }
    u[c] = make_float2(di * a0, di * a1);
}

__global__ void k_out(const unsigned long long* __restrict__ Pq,
        const float* __restrict__ dis, const float* __restrict__ degf,
        const float2* __restrict__ u, const float* __restrict__ b2,
        float2* __restrict__ out, int n, int C) {
    int c = blockIdx.x * blockDim.x + threadIdx.x;
    if (c >= n) return;
    int k = c >> CSH, l = c & (CW - 1);
    unsigned long long S = 0ull;
    for (int j = 0; j < C; ++j) S += Pq[((size_t)k * C + j) * CW + l];
    double dg = (double)degf[c] * 8388608.0;
    double sx = ((double)(unsigned int)(S & 0xffffffffULL) - dg) * (1.0 / 524288.0);
    double sy = ((double)(unsigned int)(S >> 32)            - dg) * (1.0 / 524288.0);
    float di = dis[c];
    float2 uc = u[c];
    out[c] = make_float2(b2[0] + di * ((float)sx + uc.x),
                         b2[1] + di * ((float)sy + uc.y));
}

// ---------- generic atomic fallback (any n/e, slow but correct) ----------
__global__ void f_init_deg(float* deg, int n) {
    int i = blockIdx.x * blockDim.x + threadIdx.x;
    if (i < n) deg[i] = 1.0f;
}
__global__ void f_deg(const int* col, float* deg, int e) {
    int i = blockIdx.x * blockDim.x + threadIdx.x;
    if (i < e) atomicAdd(&deg[col[i]], 1.0f);
}
__global__ void f_dis_self(const float* x, float* deg_dis, float* s, int n) {
    int i = blockIdx.x * blockDim.x + threadIdx.x;
    if (i < n) { float di = rsqrtf(deg_dis[i]); deg_dis[i] = di; s[i] = di * di * x[i]; }
}
__global__ void f_agg1(const int* row, const int* col, const float* dis,
                       const float* x, float* s, int e) {
    int i = blockIdx.x * blockDim.x + threadIdx.x;
    if (i < e) { int r = row[i], c = col[i]; atomicAdd(&s[c], dis[r] * dis[c] * x[r]); }
}
__global__ void f_mlp(const float* s, const float* dis, const float* W1,
                      const float* b1, const float* W2, const float* b2,
                      float* h2, float* out, int n) {
    int i = blockIdx.x * blockDim.x + threadIdx.x;
    if (i < n) {
        float sv = s[i], a0 = 0.0f, a1 = 0.0f;
#pragma unroll
        for (int j = 0; j < 16; ++j) {
            float h1 = fmaxf(sv * W1[j] + b1[j], 0.0f);
            a0 = fmaf(W2[j], h1, a0); a1 = fmaf(W2[16 + j], h1, a1);
        }
        h2[2 * i] = a0; h2[2 * i + 1] = a1;
        float d2 = dis[i] * dis[i];
        out[2 * i] = b2[0] + d2 * a0; out[2 * i + 1] = b2[1] + d2 * a1;
    }
}
__global__ void f_agg2(const int* row, const int* col, const float* dis,
                       const float* h2, float* out, int e) {
    int i = blockIdx.x * blockDim.x + threadIdx.x;
    if (i < e) {
        int r = row[i], c = col[i];
        float nm = dis[r] * dis[c];
        float2 hv = *reinterpret_cast<const float2*>(&h2[2 * r]);
        atomicAdd(&out[2 * c], nm * hv.x);
        atomicAdd(&out[2 * c + 1], nm * hv.y);
    }
}
// -------------------------------------------------------------------------

extern "C" void kernel_launch(void* const* d_in, const int* in_sizes, int n_in,
                              void* d_out, int out_size, void* d_ws, size_t ws_size,
                              hipStream_t stream) {
    const float* x  = (const float*)d_in[0];
    const int*   ei = (const int*)d_in[1];
    const float* W1 = (const float*)d_in[2];
    const float* b1 = (const float*)d_in[3];
    const float* W2 = (const float*)d_in[4];
    const float* b2 = (const float*)d_in[5];

    const int n = in_sizes[0];
    const int e = in_sizes[1] / 2;
    const int* row = ei;
    const int* col = ei + e;

    const int NC = (n + CW - 1) >> CSH;
    const size_t NCW = (size_t)NC * CW;

    // PAD = mean + 8*sigma + 32 (binomial tail; overflow P ~1e-12/cell)
    const int chunk = chunk_of(e);
    const int lam = NC > 0 ? chunk / NC : 0;
    int PAD = lam + 8 * (int)std::sqrt((double)(lam > 0 ? lam : 1)) + 32;
    PAD = (PAD + 3) & ~3;

    // ws (4B units): P1[NB1*NC*PAD] | CNT[NB1*NC] | dis[n] | t[n] | degf[n] | u[2n] | Pp
    const size_t ws4 = ws_size / 4;
    const size_t p1sz = (size_t)NB1 * NC * PAD;
    size_t base4 = p1sz + (size_t)NB1 * NC + 5ull * (size_t)n;
    base4 = (base4 + 3) & ~(size_t)3;
    long long avail = (long long)ws4 - (long long)base4;
    int Cs = (avail > 0) ? (int)min((long long)32, avail / (long long)NCW) : 0;
    int Cv = (avail > 0) ? (int)min((long long)24, avail / (long long)(2 * NCW)) : 0;

    // Guards: u64 packing needs indeg<256 (e<=100n); NC>=4 avoids cursor
    // same-address meltdown; ws must fit padded regions + partials.
    const int gn = (n + 255) / 256;
    if (NC > MAXNC || NC < 4 || Cs < 2 || Cv < 2 ||
        (long long)e > 100ll * (long long)n) {
        float* dis = (float*)d_ws; float* s = dis + n; float* h2 = s + n;
        const int ge = (e + 255) / 256;
        f_init_deg<<<gn, 256, 0, stream>>>(dis, n);
        f_deg<<<ge, 256, 0, stream>>>(col, dis, e);
        f_dis_self<<<gn, 256, 0, stream>>>(x, dis, s, n);
        f_agg1<<<ge, 256, 0, stream>>>(row, col, dis, x, s, e);
        f_mlp<<<gn, 256, 0, stream>>>(s, dis, W1, b1, W2, b2, h2, (float*)d_out, n);
        f_agg2<<<ge, 256, 0, stream>>>(row, col, dis, h2, (float*)d_out, e);
        return;
    }

    int*    P1   = (int*)d_ws;
    int*    CNT  = P1 + p1sz;
    float*  dis  = (float*)(CNT + (size_t)NB1 * NC);
    float*  t    = dis + n;
    float*  degf = t + n;
    float2* u    = (float2*)(degf + n);
    float*  Pp   = (float*)((char*)d_ws + base4 * 4);   // partials (int/float/u64)

    k_scatter<<<NB1, 1024, 0, stream>>>(row, col, P1, CNT, e, NC, PAD);
    k_deg    <<<NC * Cs, 512, 0, stream>>>(P1, CNT, (int*)Pp, NC, Cs, PAD);
    k_prep   <<<gn, 256, 0, stream>>>((const int*)Pp, x, dis, t, degf, n, Cs);
    k_aggf   <<<NC * Cs, 512, 0, stream>>>(P1, CNT, t, Pp, NC, Cs, PAD);
    k_mlp    <<<gn, 256, 0, stream>>>(Pp, dis, t, W1, b1, W2, u, n, Cs);
    k_agg2f  <<<NC * Cv, 512, 0, stream>>>(P1, CNT, u, (unsigned long long*)Pp, NC, Cv, PAD);
    k_out    <<<gn, 256, 0, stream>>>((const unsigned long long*)Pp, dis, degf, u, b2,
                                      (float2*)d_out, n, Cv);
}